// Round 7
// baseline (257.685 us; speedup 1.0000x reference)
//
#include <hip/hip_runtime.h>
#include <hip/hip_bf16.h>
#include <stdint.h>

#define D_IN    512
#define NTOT    32896
#define BATCH   4096
#define BM      256
#define BN      256
#define BK      64
#define NMT     16       // BATCH/BM
#define NNT     129      // ceil(32896/256): last tile ragged (128 valid cols)
#define NWG_GEMM (NMT * NNT)   // 2064, divisible by 8

typedef __attribute__((ext_vector_type(8))) short short8;
typedef __attribute__((ext_vector_type(4))) float f32x4;

__device__ __forceinline__ unsigned short f2bf(float f) {
    union { float f; uint32_t u; } v; v.f = f;
    return (unsigned short)((v.u + 0x7fffu + ((v.u >> 16) & 1u)) >> 16);
}

__global__ __launch_bounds__(256) void convx_kernel(const float* __restrict__ x,
                                                    unsigned short* __restrict__ xb) {
    int tid = blockIdx.x * 256 + threadIdx.x;
    const f32x4* xv = (const f32x4*)x;
    f32x4 a = __builtin_nontemporal_load(xv + 2 * tid);
    f32x4 c = __builtin_nontemporal_load(xv + 2 * tid + 1);
    short8 o;
    o[0] = (short)f2bf(a[0]); o[1] = (short)f2bf(a[1]);
    o[2] = (short)f2bf(a[2]); o[3] = (short)f2bf(a[3]);
    o[4] = (short)f2bf(c[0]); o[5] = (short)f2bf(c[1]);
    o[6] = (short)f2bf(c[2]); o[7] = (short)f2bf(c[3]);
    ((short8*)xb)[tid] = o;
}

// W [D_IN][NTOT] fp32 -> k-packed bf16: Wp[g][n][r] = W[g*8+r][n], g in [0,64)
__global__ __launch_bounds__(256) void convw_kernel(const float* __restrict__ W,
                                                    unsigned short* __restrict__ wp) {
    int tid = blockIdx.x * 256 + threadIdx.x;
    int g = tid / NTOT;
    int n = tid - g * NTOT;
    const float* src = W + (size_t)g * 8u * NTOT + n;
    short8 o;
#pragma unroll
    for (int r = 0; r < 8; ++r) o[r] = (short)f2bf(__builtin_nontemporal_load(src + (size_t)r * NTOT));
    ((short8*)wp)[(size_t)g * NTOT + n] = o;
}

__device__ __forceinline__ void gload16(const void* g, void* l) {
    __builtin_amdgcn_global_load_lds(
        (const __attribute__((address_space(1))) void*)g,
        (__attribute__((address_space(3))) void*)l, 16, 0, 0);
}

#define BAR()   asm volatile("s_barrier" ::: "memory")
#define VMCNT4() do { asm volatile("s_waitcnt vmcnt(4)" ::: "memory"); \
                      __builtin_amdgcn_sched_barrier(0); } while (0)
#define VMCNT0() do { asm volatile("s_waitcnt vmcnt(0)" ::: "memory"); \
                      __builtin_amdgcn_sched_barrier(0); } while (0)

// 8-phase double-buffered GEMM (T3+T4+T5 per catalog). BM=256 BN=256 BK=64,
// 8 K-tiles, 8 waves (2M x 4N), per-wave 128x64 = 8x4 frags, 16 MFMA/phase.
// LDS 128 KB: sA/sB[buf][g][row] k-packed, wave w stages k-group w (4 gload16
// per stage phase, linear dest, conflict-free ds_read_b128 — BANK_CONFLICT=0
// measured R1-R6). Stages at P1/P4/P5/P8; vmcnt(4) at P4/P8 only (3-phase
// lead, never drains to 0 in steady state).
__global__ __launch_bounds__(512, 1) void gemm_kernel(
        const unsigned short* __restrict__ Ab,   // [BATCH][D_IN] bf16
        const unsigned short* __restrict__ Bp,   // [64][NTOT][8] bf16 k-packed
        const float* __restrict__ bias,          // [NTOT] fp32
        float* __restrict__ C) {                 // [BATCH][NTOT] fp32
    extern __shared__ char smem[];
    short8 (*sA)[8][256] = reinterpret_cast<short8(*)[8][256]>(smem);           // 64 KB
    short8 (*sB)[8][256] = reinterpret_cast<short8(*)[8][256]>(smem + 65536);   // 64 KB

    const int bid = (int)blockIdx.x;
    const int xcd = bid & 7;
    const int j   = bid >> 3;             // 0..257
    const int mt  = xcd * 2 + (j & 1);    // XCD owns 2 A-bands (512 KB, L2-res)
    const int nt  = j >> 1;               // 0..128 swept in step across XCDs
    const int brow = mt * BM;
    const int bcol = nt * BN;

    const int tid  = (int)threadIdx.x;
    const int lane = tid & 63;
    const int w    = tid >> 6;      // wave 0..7, stages k-group w
    const int wm   = w >> 2;        // 0..1 : rows wm*128
    const int wn   = w & 3;         // 0..3 : cols wn*64

    const int g16 = lane >> 4;      // fragment k-subgroup
    const int fr  = lane & 15;      // fragment row/col

    f32x4 acc[8][4] = {};

    // staging sources (wave w, k-group w). A: rows j*64+lane; B: cols j*64+lane
    // with ragged-tile clamp (cols >= NTOT wrap back 128 -> duplicate valid data,
    // masked at store).
    const unsigned short* aBase = Ab + (size_t)(brow + lane) * D_IN + w * 8;
    const unsigned short* bBase[4];
#pragma unroll
    for (int jj = 0; jj < 4; ++jj) {
        int c = bcol + jj * 64 + lane;
        if (c >= NTOT) c -= 128;
        bBase[jj] = Bp + ((size_t)w * NTOT + c) * 8;
    }

#define STAGE_A(offsh, buf) do { _Pragma("unroll") \
    for (int j_ = 0; j_ < 4; ++j_) \
        gload16(aBase + (size_t)j_ * 64 * D_IN + (offsh), (void*)&sA[buf][w][j_ * 64]); \
} while (0)
#define STAGE_B(offsh, buf) do { _Pragma("unroll") \
    for (int j_ = 0; j_ < 4; ++j_) \
        gload16(bBase[j_] + (offsh), (void*)&sB[buf][w][j_ * 64]); \
} while (0)

    short8 aF[4][2], bF[4][2];

#define READ_A(buf, mh) do { _Pragma("unroll") \
    for (int mq = 0; mq < 4; ++mq) _Pragma("unroll") \
        for (int kk = 0; kk < 2; ++kk) \
            aF[mq][kk] = sA[buf][kk * 4 + g16][wm * 128 + ((mh) * 4 + mq) * 16 + fr]; \
} while (0)
#define READ_B(buf, nh) do { _Pragma("unroll") \
    for (int nq = 0; nq < 2; ++nq) _Pragma("unroll") \
        for (int kk = 0; kk < 2; ++kk) \
            bF[(nh) * 2 + nq][kk] = sB[buf][kk * 4 + g16][wn * 64 + ((nh) * 2 + nq) * 16 + fr]; \
} while (0)
#define MFMA_QUAD(mh, nh) do { \
    __builtin_amdgcn_s_setprio(1); \
    _Pragma("unroll") for (int mq = 0; mq < 4; ++mq) \
    _Pragma("unroll") for (int nq = 0; nq < 2; ++nq) \
    _Pragma("unroll") for (int kk = 0; kk < 2; ++kk) \
        acc[(mh) * 4 + mq][(nh) * 2 + nq] = __builtin_amdgcn_mfma_f32_16x16x32_bf16( \
            aF[mq][kk], bF[(nh) * 2 + nq][kk], acc[(mh) * 4 + mq][(nh) * 2 + nq], 0, 0, 0); \
    __builtin_amdgcn_s_setprio(0); \
} while (0)

    const size_t bKT = (size_t)8 * NTOT * 8;   // B shorts per K-tile

    // ---- prologue: A(0)+B(0)->buf0, A(1)->buf1; publish buf0 ----
    STAGE_A(0, 0);
    STAGE_B(0, 0);
    STAGE_A(64, 1);
    VMCNT4();                        // buf0's 8 loads drained, A(1) in flight
    BAR();

#pragma unroll 1
    for (int i = 0; i < 4; ++i) {
        const int t1 = 2 * i + 1;
        const bool more = (i < 3);

        // P1: Q(m0-3, n0-1) of buf0; stage B(t1 -> buf1)
        READ_A(0, 0); READ_B(0, 0);
        STAGE_B((size_t)t1 * bKT, 1);
        BAR();
        MFMA_QUAD(0, 0);
        BAR();
        // P2: Q(m0-3, n2-3)
        READ_B(0, 1);
        BAR();
        MFMA_QUAD(0, 1);
        BAR();
        // P3: Q(m4-7, n0-1)
        READ_A(0, 1);
        BAR();
        MFMA_QUAD(1, 0);
        BAR();
        // P4: Q(m4-7, n2-3); stage A(t0+2 -> buf0); publish buf1
        if (more) { STAGE_A((size_t)(t1 + 1) * 64, 0); VMCNT4(); }
        else      { VMCNT0(); }
        BAR();
        MFMA_QUAD(1, 1);
        BAR();

        // P5: Q(m0-3, n0-1) of buf1; stage B(t0+2 -> buf0)
        READ_A(1, 0); READ_B(1, 0);
        if (more) STAGE_B((size_t)(t1 + 1) * bKT, 0);
        BAR();
        MFMA_QUAD(0, 0);
        BAR();
        // P6
        READ_B(1, 1);
        BAR();
        MFMA_QUAD(0, 1);
        BAR();
        // P7
        READ_A(1, 1);
        BAR();
        MFMA_QUAD(1, 0);
        BAR();
        // P8: stage A(t1+2 -> buf1); publish buf0(t0+2)
        if (more) { STAGE_A((size_t)(t1 + 2) * 64, 1); VMCNT4(); }
        BAR();
        MFMA_QUAD(1, 1);
        BAR();
    }

    // ---- epilogue: per-wave LDS transpose -> masked full-line nt stores ----
    // acc[m][n][q] = C[row = wm*128 + m*16 + (lane>>4)*4 + q][col = wn*64 + n*16 + fr]
    float bv[4];
#pragma unroll
    for (int n = 0; n < 4; ++n) {
        int c = bcol + wn * 64 + n * 16 + fr;
        if (c >= NTOT) c -= 128;     // clamp (masked at store)
        bv[n] = bias[c];
    }

    float* tw = reinterpret_cast<float*>(smem) + w * 1088;  // 16 rows x 68 f32
    const int rl = lane >> 3;       // 0..7
    const int c8 = lane & 7;        // 0..7
#pragma unroll
    for (int m = 0; m < 8; ++m) {
#pragma unroll
        for (int n = 0; n < 4; ++n)
#pragma unroll
            for (int q = 0; q < 4; ++q)
                tw[((lane >> 4) * 4 + q) * 68 + fr + 16 * n] = acc[m][n][q] + bv[n];
#pragma unroll
        for (int rg = 0; rg < 2; ++rg)
#pragma unroll
            for (int h = 0; h < 2; ++h) {
                f32x4 v = *(const f32x4*)&tw[(rg * 8 + rl) * 68 + (c8 + 8 * h) * 4];
                const int col4 = bcol + wn * 64 + (c8 + 8 * h) * 4;
                if (col4 < NTOT) {
                    float* dst = C + (size_t)(brow + wm * 128 + m * 16 + rg * 8 + rl) * NTOT + col4;
                    __builtin_nontemporal_store(v, (f32x4*)dst);
                }
            }
    }
}

extern "C" void kernel_launch(void* const* d_in, const int* in_sizes, int n_in,
                              void* d_out, int out_size, void* d_ws, size_t ws_size,
                              hipStream_t stream) {
    const float* x = (const float*)d_in[0];
    const float* W = (const float*)d_in[1];
    const float* b = (const float*)d_in[2];
    float* out = (float*)d_out;

    unsigned short* xb = (unsigned short*)d_ws;               // 4 MB
    unsigned short* wp = xb + (size_t)BATCH * D_IN;           // +33.7 MB

    convx_kernel<<<(BATCH * D_IN / 8) / 256, 256, 0, stream>>>(x, xb);
    convw_kernel<<<((D_IN / 8) * NTOT) / 256, 256, 0, stream>>>(W, wp);

    const int lds_bytes = 131072;   // 2 buf x (32 KB A + 32 KB B)
    hipFuncSetAttribute((const void*)gemm_kernel,
                        hipFuncAttributeMaxDynamicSharedMemorySize, lds_bytes);
    gemm_kernel<<<NWG_GEMM, 512, lds_bytes, stream>>>(xb, wp, b, out);
}

// Round 8
// 235.945 us; speedup vs baseline: 1.0921x; 1.0921x over previous
//
#include <hip/hip_runtime.h>
#include <hip/hip_bf16.h>
#include <stdint.h>

#define D_IN    512
#define NTOT    32896
#define BATCH   4096
#define NWG_GEMM 8224   // 32 m-tiles * 257 n-tiles

typedef __attribute__((ext_vector_type(8))) short short8;
typedef __attribute__((ext_vector_type(4))) float f32x4;
typedef __attribute__((ext_vector_type(16))) float f32x16;

__device__ __forceinline__ unsigned short f2bf(float f) {
    union { float f; uint32_t u; } v; v.f = f;
    return (unsigned short)((v.u + 0x7fffu + ((v.u >> 16) & 1u)) >> 16);
}

__global__ __launch_bounds__(256) void convx_kernel(const float* __restrict__ x,
                                                    unsigned short* __restrict__ xb) {
    int tid = blockIdx.x * 256 + threadIdx.x;
    const f32x4* xv = (const f32x4*)x;
    f32x4 a = __builtin_nontemporal_load(xv + 2 * tid);
    f32x4 c = __builtin_nontemporal_load(xv + 2 * tid + 1);
    short8 o;
    o[0] = (short)f2bf(a[0]); o[1] = (short)f2bf(a[1]);
    o[2] = (short)f2bf(a[2]); o[3] = (short)f2bf(a[3]);
    o[4] = (short)f2bf(c[0]); o[5] = (short)f2bf(c[1]);
    o[6] = (short)f2bf(c[2]); o[7] = (short)f2bf(c[3]);
    ((short8*)xb)[tid] = o;
}

// W [D_IN][NTOT] fp32 -> k-packed bf16: Wp[g][n][r] = W[g*8+r][n], g in [0,64)
__global__ __launch_bounds__(256) void convw_kernel(const float* __restrict__ W,
                                                    unsigned short* __restrict__ wp) {
    int tid = blockIdx.x * 256 + threadIdx.x;
    int g = tid / NTOT;
    int n = tid - g * NTOT;
    const float* src = W + (size_t)g * 8u * NTOT + n;
    short8 o;
#pragma unroll
    for (int r = 0; r < 8; ++r) o[r] = (short)f2bf(__builtin_nontemporal_load(src + (size_t)r * NTOT));
    ((short8*)wp)[(size_t)g * NTOT + n] = o;
}

__device__ __forceinline__ void gload16(const void* g, void* l) {
    __builtin_amdgcn_global_load_lds(
        (const __attribute__((address_space(1))) void*)g,
        (__attribute__((address_space(3))) void*)l, 16, 0, 0);
}

// C[M][N] = Ab * Wp + bias. R6-proven structure: 128x128 tile, BK=32,
// double-buffered LDS (32 KB), 4 waves 2x2, wave-tile 64x64.
// R8 changes: (1) mfma_f32_32x32x16_bf16 (2x2 sub-tiles/wave, 8 MFMA/K-tile
// instead of 16, +15% µbench rate, acc=64 VGPR); (2) epilogue transpose for
// the 32x32 C/D layout (col=lane&31, row=(reg&3)+8*(reg>>2)+4*(lane>>5),
// m74/m101-verified), stride-40 f32 LDS (bank-uniform, 16B-aligned), full
// 128B-line nontemporal stores; (3) per-XCD nt stagger (+xcd*32 mod 257).
__global__ __launch_bounds__(256, 3) void gemm_kernel(
        const unsigned short* __restrict__ Ab,   // [BATCH][D_IN] bf16
        const unsigned short* __restrict__ Bp,   // [64][NTOT][8] bf16 k-packed
        const float* __restrict__ bias,          // [NTOT] fp32
        float* __restrict__ C) {                 // [BATCH][NTOT] fp32
    __shared__ __align__(16) char smem_raw[32768];
    short8 (*sA)[4][128] = reinterpret_cast<short8(*)[4][128]>(smem_raw);          // 16 KB
    short8 (*sB)[4][128] = reinterpret_cast<short8(*)[4][128]>(smem_raw + 16384);  // 16 KB

    const int bid = (int)blockIdx.x;
    const int xcd = bid & 7;
    const int j   = bid >> 3;                    // 0..1027
    const int mt  = xcd * 4 + (j & 3);           // XCD-exclusive 4-mt A band (512 KB)
    const int nt  = ((j >> 2) + xcd * 32) % 257; // staggered B-panel sweep per XCD
    const int brow = mt * 128;
    const int bcol = nt * 128;

    const int tid  = (int)threadIdx.x;
    const int lane = tid & 63;
    const int w    = tid >> 6;      // wave 0..3
    const int wr   = w >> 1;        // wave row (0,1)
    const int wc   = w & 1;         // wave col (0,1)

    f32x16 acc[2][2] = {};

    // Staging: wave w owns k-group g=w of both tiles, halves h=0,1 (as R6).
    const unsigned short* gA0 = Ab + (size_t)(brow + lane) * D_IN + w * 8;
    const unsigned short* gA1 = Ab + (size_t)(brow + 64 + lane) * D_IN + w * 8;
    const unsigned short* gB0 = Bp + ((size_t)w * NTOT + bcol + lane) * 8;
    const unsigned short* gB1 = Bp + ((size_t)w * NTOT + bcol + 64 + lane) * 8;
    const size_t bstep = (size_t)4 * NTOT * 8;   // advance 4 k-groups

    const int l5  = lane >> 5;      // k-half selector for 32x32x16 operands
    const int l31 = lane & 31;      // row (A) / col (B) within fragment

    // --- prologue: stage K-tile 0 into buffer 0 ---
    gload16(gA0, (void*)&sA[0][w][0]);
    gload16(gA1, (void*)&sA[0][w][64]);
    gload16(gB0, (void*)&sB[0][w][0]);
    gload16(gB1, (void*)&sB[0][w][64]);
    gA0 += 32; gA1 += 32; gB0 += bstep; gB1 += bstep;
    __syncthreads();

    int cur = 0;
    for (int it = 0; it < 16; ++it) {
        if (it < 15) {
            const int nxt = cur ^ 1;
            gload16(gA0, (void*)&sA[nxt][w][0]);
            gload16(gA1, (void*)&sA[nxt][w][64]);
            gload16(gB0, (void*)&sB[nxt][w][0]);
            gload16(gB1, (void*)&sB[nxt][w][64]);
            gA0 += 32; gA1 += 32; gB0 += bstep; gB1 += bstep;
        }

        // 32x32x16 operands: lane holds 8 bf16 at rows/cols (lane&31),
        // k-group 2*ks + (lane>>5) -> exactly one k-packed short8.
        short8 aF[2][2], bF[2][2];
#pragma unroll
        for (int ks = 0; ks < 2; ++ks) {
#pragma unroll
            for (int mi = 0; mi < 2; ++mi)
                aF[mi][ks] = sA[cur][2 * ks + l5][wr * 64 + mi * 32 + l31];
#pragma unroll
            for (int ni = 0; ni < 2; ++ni)
                bF[ni][ks] = sB[cur][2 * ks + l5][wc * 64 + ni * 32 + l31];
        }
#pragma unroll
        for (int mi = 0; mi < 2; ++mi)
#pragma unroll
            for (int ni = 0; ni < 2; ++ni)
#pragma unroll
                for (int ks = 0; ks < 2; ++ks)
                    acc[mi][ni] = __builtin_amdgcn_mfma_f32_32x32x16_bf16(
                        aF[mi][ks], bF[ni][ks], acc[mi][ni], 0, 0, 0);

        __syncthreads();
        cur ^= 1;
    }
    // final __syncthreads drained all LDS reads -> smem reusable for transpose.

    // ---- epilogue: per-wave LDS transpose -> full-line nt stores ----
    // 32x32 C/D layout (m74/m101): col = lane&31,
    //                              row = (reg&3) + 8*(reg>>2) + 4*(lane>>5).
    float* tw = reinterpret_cast<float*>(smem_raw) + w * 1280;  // 32 rows x 40 f32
    const int rl = lane >> 3;       // 0..7
    const int c8 = lane & 7;        // 0..7
#pragma unroll
    for (int mi = 0; mi < 2; ++mi)
#pragma unroll
        for (int ni = 0; ni < 2; ++ni) {
            const float bv = bias[bcol + wc * 64 + ni * 32 + l31];
            // scatter 32x32 chunk (stride 40: both phases bank-uniform)
#pragma unroll
            for (int r = 0; r < 16; ++r) {
                const int row_l = (r & 3) + 8 * (r >> 2) + 4 * l5;
                tw[row_l * 40 + l31] = acc[mi][ni][r] + bv;
            }
            // gather rows: each instr = 8 rows x one full 128 B line
#pragma unroll
            for (int rg = 0; rg < 4; ++rg) {
                const int row_l = rg * 8 + rl;
                f32x4 v = *(const f32x4*)&tw[row_l * 40 + c8 * 4];
                float* dst = C + (size_t)(brow + wr * 64 + mi * 32 + row_l) * NTOT
                               + bcol + wc * 64 + ni * 32 + c8 * 4;
                __builtin_nontemporal_store(v, (f32x4*)dst);
            }
        }
}

extern "C" void kernel_launch(void* const* d_in, const int* in_sizes, int n_in,
                              void* d_out, int out_size, void* d_ws, size_t ws_size,
                              hipStream_t stream) {
    const float* x = (const float*)d_in[0];
    const float* W = (const float*)d_in[1];
    const float* b = (const float*)d_in[2];
    float* out = (float*)d_out;

    unsigned short* xb = (unsigned short*)d_ws;               // 4 MB
    unsigned short* wp = xb + (size_t)BATCH * D_IN;           // +33.7 MB

    convx_kernel<<<(BATCH * D_IN / 8) / 256, 256, 0, stream>>>(x, xb);
    convw_kernel<<<((D_IN / 8) * NTOT) / 256, 256, 0, stream>>>(W, wp);
    gemm_kernel<<<NWG_GEMM, 256, 0, stream>>>(xb, wp, b, out);
}

// Round 9
// 233.733 us; speedup vs baseline: 1.1025x; 1.0095x over previous
//
#include <hip/hip_runtime.h>
#include <hip/hip_bf16.h>
#include <stdint.h>

#define D_IN    512
#define NTOT    32896
#define BATCH   4096
#define NWG_GEMM 8224   // 32 m-tiles * 257 n-tiles

typedef __attribute__((ext_vector_type(8))) short short8;
typedef __attribute__((ext_vector_type(4))) float f32x4;

__device__ __forceinline__ unsigned short f2bf(float f) {
    union { float f; uint32_t u; } v; v.f = f;
    return (unsigned short)((v.u + 0x7fffu + ((v.u >> 16) & 1u)) >> 16);
}

__global__ __launch_bounds__(256) void convx_kernel(const float* __restrict__ x,
                                                    unsigned short* __restrict__ xb) {
    int tid = blockIdx.x * 256 + threadIdx.x;
    const f32x4* xv = (const f32x4*)x;
    f32x4 a = __builtin_nontemporal_load(xv + 2 * tid);
    f32x4 c = __builtin_nontemporal_load(xv + 2 * tid + 1);
    short8 o;
    o[0] = (short)f2bf(a[0]); o[1] = (short)f2bf(a[1]);
    o[2] = (short)f2bf(a[2]); o[3] = (short)f2bf(a[3]);
    o[4] = (short)f2bf(c[0]); o[5] = (short)f2bf(c[1]);
    o[6] = (short)f2bf(c[2]); o[7] = (short)f2bf(c[3]);
    ((short8*)xb)[tid] = o;
}

// W [D_IN][NTOT] fp32 -> k-packed bf16: Wp[g][n][r] = W[g*8+r][n], g in [0,64)
__global__ __launch_bounds__(256) void convw_kernel(const float* __restrict__ W,
                                                    unsigned short* __restrict__ wp) {
    int tid = blockIdx.x * 256 + threadIdx.x;
    int g = tid / NTOT;
    int n = tid - g * NTOT;
    const float* src = W + (size_t)g * 8u * NTOT + n;
    short8 o;
#pragma unroll
    for (int r = 0; r < 8; ++r) o[r] = (short)f2bf(__builtin_nontemporal_load(src + (size_t)r * NTOT));
    ((short8*)wp)[(size_t)g * NTOT + n] = o;
}

__device__ __forceinline__ void gload16(const void* g, void* l) {
    __builtin_amdgcn_global_load_lds(
        (const __attribute__((address_space(1))) void*)g,
        (__attribute__((address_space(3))) void*)l, 16, 0, 0);
}

// C[M][N] = Ab * Wp + bias. R6 geometry (128x128 tile, BK=32, 4 waves 2x2,
// wave-tile 64x64, 16x16x32 MFMA, k-packed conflict-free LDS, gload_lds,
// LDS-transpose full-line epilogue, XCD-banded A) with R9's change:
// *** 3-buffer / 2-tile-lead pipeline with COUNTED vmcnt (T4) ***
//   iter t: s_waitcnt vmcnt(4)   (drains tile t; tile t+1 stays in flight)
//           s_barrier
//           STAGE(t+2 -> buf (t+2)%3)   (4 gload16 per wave)
//           ds_read + 16 MFMA on buf t%3
// One barrier per iteration; staged loads span ~2 iterations of compute.
__global__ __launch_bounds__(256, 3) void gemm_kernel(
        const unsigned short* __restrict__ Ab,   // [BATCH][D_IN] bf16
        const unsigned short* __restrict__ Bp,   // [64][NTOT][8] bf16 k-packed
        const float* __restrict__ bias,          // [NTOT] fp32
        float* __restrict__ C) {                 // [BATCH][NTOT] fp32
    __shared__ __align__(16) char smem_raw[49152];
    short8 (*sA)[4][128] = reinterpret_cast<short8(*)[4][128]>(smem_raw);          // 24 KB
    short8 (*sB)[4][128] = reinterpret_cast<short8(*)[4][128]>(smem_raw + 24576);  // 24 KB

    const int bid = (int)blockIdx.x;
    const int xcd = bid & 7;
    const int j   = bid >> 3;          // 0..1027
    const int mt  = xcd * 4 + (j & 3); // XCD-exclusive 4-mt A band (512 KB, L2)
    const int nt  = j >> 2;            // 0..256 swept in step across XCDs
    const int brow = mt * 128;
    const int bcol = nt * 128;

    const int tid  = (int)threadIdx.x;
    const int lane = tid & 63;
    const int w    = tid >> 6;      // wave 0..3; stages k-group (4t + w)
    const int wr   = w >> 1;        // wave row (0,1)
    const int wc   = w & 1;         // wave col (0,1)

    f32x4 acc[4][4] = {};

    // staging bases (tile t adds: A += t*32 shorts; B += t*4*NTOT*8 shorts)
    const unsigned short* aB0 = Ab + (size_t)(brow + lane) * D_IN + w * 8;
    const unsigned short* aB1 = Ab + (size_t)(brow + 64 + lane) * D_IN + w * 8;
    const unsigned short* bB0 = Bp + ((size_t)w * NTOT + bcol + lane) * 8;
    const unsigned short* bB1 = Bp + ((size_t)w * NTOT + bcol + 64 + lane) * 8;

#define STAGE(t, c) do {                                                   \
    gload16(aB0 + (size_t)(t) * 32,            (void*)&sA[c][w][0]);       \
    gload16(aB1 + (size_t)(t) * 32,            (void*)&sA[c][w][64]);      \
    gload16(bB0 + (size_t)(t) * 4 * NTOT * 8,  (void*)&sB[c][w][0]);       \
    gload16(bB1 + (size_t)(t) * 4 * NTOT * 8,  (void*)&sB[c][w][64]);      \
} while (0)

    const int g  = lane >> 4;       // k-group of this lane's fragment
    const int fr = lane & 15;       // row (A) / col (B) within fragment

    // --- prologue: tiles 0,1 in flight (8 loads/wave) ---
    STAGE(0, 0);
    STAGE(1, 1);

#pragma unroll
    for (int t = 0; t < 16; ++t) {
        const int c = t % 3;
        // counted drain: exactly tile t's 4 loads; t+1's stay in flight
        if (t < 15) asm volatile("s_waitcnt vmcnt(4)" ::: "memory");
        else        asm volatile("s_waitcnt vmcnt(0)" ::: "memory");
        __builtin_amdgcn_sched_barrier(0);
        __builtin_amdgcn_s_barrier();        // tile t resident for all waves
        // stage tile t+2 (its buf's last readers finished before the barrier)
        if (t < 14) STAGE(t + 2, (t + 2) % 3);

        short8 aF[4], bF[4];
#pragma unroll
        for (int m = 0; m < 4; ++m) aF[m] = sA[c][g][wr * 64 + m * 16 + fr];
#pragma unroll
        for (int n = 0; n < 4; ++n) bF[n] = sB[c][g][wc * 64 + n * 16 + fr];
#pragma unroll
        for (int m = 0; m < 4; ++m)
#pragma unroll
            for (int n = 0; n < 4; ++n)
                acc[m][n] = __builtin_amdgcn_mfma_f32_16x16x32_bf16(
                    aF[m], bF[n], acc[m][n], 0, 0, 0);
    }
#undef STAGE
    __builtin_amdgcn_s_barrier();            // all MFMA reads done -> smem reusable

    // ---- epilogue: per-wave LDS transpose -> full-line nt stores (R6) ----
    // frag layout: acc[m][n][q] = C[wr*64+m*16+(lane>>4)*4+q][wc*64+n*16+fr]
    const int colb = bcol + wc * 64 + fr;
    float bv[4];
#pragma unroll
    for (int n = 0; n < 4; ++n) bv[n] = bias[colb + n * 16];

    float* tw = reinterpret_cast<float*>(smem_raw) + w * 1088;  // 16 rows x 68
    const int rl = lane >> 3;       // 0..7
    const int c8 = lane & 7;        // 0..7
#pragma unroll
    for (int m = 0; m < 4; ++m) {
#pragma unroll
        for (int n = 0; n < 4; ++n)
#pragma unroll
            for (int q = 0; q < 4; ++q)
                tw[((lane >> 4) * 4 + q) * 68 + fr + 16 * n] = acc[m][n][q] + bv[n];
#pragma unroll
        for (int rg = 0; rg < 2; ++rg)
#pragma unroll
            for (int h = 0; h < 2; ++h) {
                f32x4 v = *(const f32x4*)&tw[(rg * 8 + rl) * 68 + (c8 + 8 * h) * 4];
                float* dst = C + (size_t)(brow + wr * 64 + m * 16 + rg * 8 + rl) * NTOT
                               + bcol + wc * 64 + (c8 + 8 * h) * 4;
                __builtin_nontemporal_store(v, (f32x4*)dst);
            }
    }
}

extern "C" void kernel_launch(void* const* d_in, const int* in_sizes, int n_in,
                              void* d_out, int out_size, void* d_ws, size_t ws_size,
                              hipStream_t stream) {
    const float* x = (const float*)d_in[0];
    const float* W = (const float*)d_in[1];
    const float* b = (const float*)d_in[2];
    float* out = (float*)d_out;

    unsigned short* xb = (unsigned short*)d_ws;               // 4 MB
    unsigned short* wp = xb + (size_t)BATCH * D_IN;           // +33.7 MB

    convx_kernel<<<(BATCH * D_IN / 8) / 256, 256, 0, stream>>>(x, xb);
    convw_kernel<<<((D_IN / 8) * NTOT) / 256, 256, 0, stream>>>(W, wp);
    gemm_kernel<<<NWG_GEMM, 256, 0, stream>>>(xb, wp, b, out);
}

// Round 10
// 228.529 us; speedup vs baseline: 1.1276x; 1.0228x over previous
//
#include <hip/hip_runtime.h>
#include <hip/hip_bf16.h>
#include <stdint.h>

#define D_IN    512
#define NTOT    32896
#define BATCH   4096
#define NWG_GEMM 8224   // 32 m-tiles * 257 n-tiles
#define NWG_CONVW 8224  // (64*32896)/256
#define NWG_CONVX 1024  // (4096*512/8)/256

typedef __attribute__((ext_vector_type(8))) short short8;
typedef __attribute__((ext_vector_type(4))) float f32x4;

__device__ __forceinline__ unsigned short f2bf(float f) {
    union { float f; uint32_t u; } v; v.f = f;
    return (unsigned short)((v.u + 0x7fffu + ((v.u >> 16) & 1u)) >> 16);
}

// Fused conversion: blocks [0, NWG_CONVW) convert W -> k-packed bf16,
// blocks [NWG_CONVW, +NWG_CONVX) convert x -> bf16 (fills idle CUs).
__global__ __launch_bounds__(256) void conv_fused(const float* __restrict__ x,
                                                  const float* __restrict__ W,
                                                  unsigned short* __restrict__ xb,
                                                  unsigned short* __restrict__ wp) {
    const int b = (int)blockIdx.x;
    if (b < NWG_CONVW) {
        // W [D_IN][NTOT] fp32 -> Wp[g][n][r] = W[g*8+r][n]
        int tid = b * 256 + (int)threadIdx.x;
        int g = tid / NTOT;
        int n = tid - g * NTOT;
        const float* src = W + (size_t)g * 8u * NTOT + n;
        short8 o;
#pragma unroll
        for (int r = 0; r < 8; ++r)
            o[r] = (short)f2bf(__builtin_nontemporal_load(src + (size_t)r * NTOT));
        ((short8*)wp)[(size_t)g * NTOT + n] = o;
    } else {
        int tid = (b - NWG_CONVW) * 256 + (int)threadIdx.x;
        const f32x4* xv = (const f32x4*)x;
        f32x4 a = __builtin_nontemporal_load(xv + 2 * tid);
        f32x4 c = __builtin_nontemporal_load(xv + 2 * tid + 1);
        short8 o;
        o[0] = (short)f2bf(a[0]); o[1] = (short)f2bf(a[1]);
        o[2] = (short)f2bf(a[2]); o[3] = (short)f2bf(a[3]);
        o[4] = (short)f2bf(c[0]); o[5] = (short)f2bf(c[1]);
        o[6] = (short)f2bf(c[2]); o[7] = (short)f2bf(c[3]);
        ((short8*)xb)[tid] = o;
    }
}

__device__ __forceinline__ void gload16(const void* g, void* l) {
    __builtin_amdgcn_global_load_lds(
        (const __attribute__((address_space(1))) void*)g,
        (__attribute__((address_space(3))) void*)l, 16, 0, 0);
}

// C[M][N] = Ab * Wp + bias. R6-proven structure: 128x128 tile, BK=32,
// double-buffered LDS (32 KB), 4 waves 2x2, wave-tile 64x64, 16x16x32 MFMA,
// k-packed conflict-free LDS, XCD-banded A, LDS-transpose full-line epilogue.
// R10 change: __launch_bounds__(256,4) -> 4 blocks/CU (128 KB LDS, 16 waves)
// for more cross-block epilogue/mainloop overlap.
__global__ __launch_bounds__(256, 4) void gemm_kernel(
        const unsigned short* __restrict__ Ab,   // [BATCH][D_IN] bf16
        const unsigned short* __restrict__ Bp,   // [64][NTOT][8] bf16 k-packed
        const float* __restrict__ bias,          // [NTOT] fp32
        float* __restrict__ C) {                 // [BATCH][NTOT] fp32
    __shared__ __align__(16) char smem_raw[32768];
    short8 (*sA)[4][128] = reinterpret_cast<short8(*)[4][128]>(smem_raw);          // 16 KB
    short8 (*sB)[4][128] = reinterpret_cast<short8(*)[4][128]>(smem_raw + 16384);  // 16 KB

    const int bid = (int)blockIdx.x;
    const int xcd = bid & 7;
    const int j   = bid >> 3;          // 0..1027
    const int mt  = xcd * 4 + (j & 3); // XCD-exclusive 4-mt A band (512 KB, L2)
    const int nt  = j >> 2;            // 0..256, swept in step across XCDs
    const int brow = mt * 128;
    const int bcol = nt * 128;

    const int tid  = (int)threadIdx.x;
    const int lane = tid & 63;
    const int w    = tid >> 6;      // wave 0..3
    const int wr   = w >> 1;        // wave row (0,1)
    const int wc   = w & 1;         // wave col (0,1)

    f32x4 acc[4][4] = {};

    const unsigned short* gA0 = Ab + (size_t)(brow + lane) * D_IN + w * 8;
    const unsigned short* gA1 = Ab + (size_t)(brow + 64 + lane) * D_IN + w * 8;
    const unsigned short* gB0 = Bp + ((size_t)w * NTOT + bcol + lane) * 8;
    const unsigned short* gB1 = Bp + ((size_t)w * NTOT + bcol + 64 + lane) * 8;
    const size_t bstep = (size_t)4 * NTOT * 8;

    const int g  = lane >> 4;
    const int fr = lane & 15;

    // --- prologue: stage K-tile 0 into buffer 0 ---
    gload16(gA0, (void*)&sA[0][w][0]);
    gload16(gA1, (void*)&sA[0][w][64]);
    gload16(gB0, (void*)&sB[0][w][0]);
    gload16(gB1, (void*)&sB[0][w][64]);
    gA0 += 32; gA1 += 32; gB0 += bstep; gB1 += bstep;
    __syncthreads();

    int cur = 0;
    for (int it = 0; it < 16; ++it) {
        if (it < 15) {
            const int nxt = cur ^ 1;
            gload16(gA0, (void*)&sA[nxt][w][0]);
            gload16(gA1, (void*)&sA[nxt][w][64]);
            gload16(gB0, (void*)&sB[nxt][w][0]);
            gload16(gB1, (void*)&sB[nxt][w][64]);
            gA0 += 32; gA1 += 32; gB0 += bstep; gB1 += bstep;
        }

        short8 aF[4], bF[4];
#pragma unroll
        for (int m = 0; m < 4; ++m) aF[m] = sA[cur][g][wr * 64 + m * 16 + fr];
#pragma unroll
        for (int n = 0; n < 4; ++n) bF[n] = sB[cur][g][wc * 64 + n * 16 + fr];
#pragma unroll
        for (int m = 0; m < 4; ++m)
#pragma unroll
            for (int n = 0; n < 4; ++n)
                acc[m][n] = __builtin_amdgcn_mfma_f32_16x16x32_bf16(
                    aF[m], bF[n], acc[m][n], 0, 0, 0);

        __syncthreads();
        cur ^= 1;
    }
    // final __syncthreads drained all LDS reads -> smem reusable for transpose.

    // ---- epilogue: per-wave LDS transpose -> full-line nt stores ----
    // frag layout: acc[m][n][q] = C[wr*64+m*16+(lane>>4)*4+q][wc*64+n*16+fr]
    const int colb = bcol + wc * 64 + fr;
    float bv[4];
#pragma unroll
    for (int n = 0; n < 4; ++n) bv[n] = bias[colb + n * 16];

    float* tw = reinterpret_cast<float*>(smem_raw) + w * 1088;  // 16 rows x 68
    const int rl = lane >> 3;       // 0..7
    const int c8 = lane & 7;        // 0..7
#pragma unroll
    for (int m = 0; m < 4; ++m) {
#pragma unroll
        for (int n = 0; n < 4; ++n)
#pragma unroll
            for (int q = 0; q < 4; ++q)
                tw[((lane >> 4) * 4 + q) * 68 + fr + 16 * n] = acc[m][n][q] + bv[n];
#pragma unroll
        for (int rg = 0; rg < 2; ++rg)
#pragma unroll
            for (int h = 0; h < 2; ++h) {
                f32x4 v = *(const f32x4*)&tw[(rg * 8 + rl) * 68 + (c8 + 8 * h) * 4];
                float* dst = C + (size_t)(brow + wr * 64 + m * 16 + rg * 8 + rl) * NTOT
                               + bcol + wc * 64 + (c8 + 8 * h) * 4;
                __builtin_nontemporal_store(v, (f32x4*)dst);
            }
    }
}

extern "C" void kernel_launch(void* const* d_in, const int* in_sizes, int n_in,
                              void* d_out, int out_size, void* d_ws, size_t ws_size,
                              hipStream_t stream) {
    const float* x = (const float*)d_in[0];
    const float* W = (const float*)d_in[1];
    const float* b = (const float*)d_in[2];
    float* out = (float*)d_out;

    unsigned short* xb = (unsigned short*)d_ws;               // 4 MB
    unsigned short* wp = xb + (size_t)BATCH * D_IN;           // +33.7 MB

    conv_fused<<<NWG_CONVW + NWG_CONVX, 256, 0, stream>>>(x, W, xb, wp);
    gemm_kernel<<<NWG_GEMM, 256, 0, stream>>>(xb, wp, b, out);
}